// Round 8
// baseline (101.902 us; speedup 1.0000x reference)
//
#include <hip/hip_runtime.h>
#include <math.h>

// Problem constants (fixed by reference)
constexpr int N_ = 4, P_ = 64, Z_ = 32, Y_ = 128, X_ = 128;
constexpr float EPSF = 1e-8f;
constexpr float INV2S2 = 0.125f;   // 1/(2*sigma^2), sigma = 2

// ws layout (floats): m[256] accumulators, then cnt[1] block counter.
// BOTH rely on the fp32 poison-bias trick: 0xAAAAAAAA == -3.03e-13f, so
// accumulating onto the poisoned base adds a negligible bias (m is O(0.1-10),
// threshold 0.1525; counter test uses +-0.5 window). Robust to 0xAA or 0x00.
constexpr int M_OFF   = 0;
constexpr int CNT_OFF = 256;

// ---------------------------------------------------------------------------
// Single fused kernel (R5 inner loop — best measured — + in-kernel finish).
// Grid: 512 blocks = (n, z, y-half, x-half); 256 threads = 4 waves.
// Each wave owns one y-row per pass (16 passes), each thread one x-column.
// kzy[row][p] tile in LDS (16/thread exps); kxr[p] in VGPRs (64/thread).
// Separable exp product == reference single exp to ~ulp above the 1e-8
// denom floor. kkx[p]=kzy*kxr once/pass; denom = 4-way partial sum of it;
// macc += kkx*w reuses it; one fp32 divide per voxel.
//
// Epilogue: butterfly array-halving reduction (R5 win: 63 shuffles/thread),
// then 64 fp32 atomicAdds into m[n*64+p] (poison-bias base, no pre-zero),
// __threadfence(), fp32 counter add; the 512th block (old ~= 511.0)
// acquire-fences and computes loss = mean(-log(max(m,EPS))) -> out[0].
// This removes the k_finish dispatch + 128 KB part round-trip vs R5.
// ---------------------------------------------------------------------------
__global__ __launch_bounds__(256, 2) void k_fused(const float* __restrict__ logits,
                                                  const float* __restrict__ pts,
                                                  float* __restrict__ ws,
                                                  float* __restrict__ out) {
    float* m   = ws + M_OFF;
    float* cnt = ws + CNT_OFF;

    const int b = blockIdx.x;          // 512 blocks: [n:2][z:5][yh:1][xh:1]
    const int n  = b >> 7;
    const int z  = (b >> 2) & 31;
    const int y0 = ((b >> 1) & 1) * 64;
    const int x0 = (b & 1) * 64;

    const int tid = threadIdx.x;
    const int lane = tid & 63;
    const int wid = tid >> 6;

    __shared__ float ptsn[192];        // pts[n] = [64][3]
    __shared__ float kzy[64 * 64];     // [row][p], 16 KB
    __shared__ float wsum[4][64];
    __shared__ int s_last;

    if (tid < 192) ptsn[tid] = pts[n * 192 + tid];
    __syncthreads();

    // kzy tile: 4096 exps / 256 threads = 16 per thread.
    for (int i = tid; i < 64 * 64; i += 256) {
        int row = i >> 6, p = i & 63;  // ptsn stride-3 reads: 2-way alias, free
        float dz = (float)z - ptsn[p * 3 + 0];
        float dy = (float)(y0 + row) - ptsn[p * 3 + 1];
        kzy[i] = __expf(-(dz * dz + dy * dy) * INV2S2);
    }

    const int x = x0 + lane;
    float kxr[64], macc[64];
    #pragma unroll
    for (int p = 0; p < 64; ++p) {
        float dx = (float)x - ptsn[p * 3 + 2];
        kxr[p] = __expf(-dx * dx * INV2S2);
        macc[p] = 0.0f;
    }
    __syncthreads();

    const float* lbase = logits + (size_t)((n * Z_ + z) * Y_ + y0) * X_ + x;

    float lg = lbase[wid * X_];        // prefetch pass-0 logit
    #pragma unroll 1
    for (int pass = 0; pass < 16; ++pass) {
        const int row = pass * 4 + wid;           // wave-uniform row
        float lg_next = 0.0f;
        if (pass < 15) lg_next = lbase[(row + 4) * X_];   // prefetch next pass

        const float4* kr = (const float4*)(&kzy[row * 64]);
        float kkx[64];
        float d0 = 0.f, d1 = 0.f, d2 = 0.f, d3 = 0.f;
        #pragma unroll
        for (int q = 0; q < 16; ++q) {
            const float4 k4 = kr[q];              // broadcast b128 read
            kkx[4*q+0] = k4.x * kxr[4*q+0]; d0 += kkx[4*q+0];
            kkx[4*q+1] = k4.y * kxr[4*q+1]; d1 += kkx[4*q+1];
            kkx[4*q+2] = k4.z * kxr[4*q+2]; d2 += kkx[4*q+2];
            kkx[4*q+3] = k4.w * kxr[4*q+3]; d3 += kkx[4*q+3];
        }
        const float denom = (d0 + d1) + (d2 + d3);
        // w = sigmoid(lg) / max(denom, EPS): one fp32 divide
        const float w = 1.0f / ((1.0f + __expf(-lg)) * fmaxf(denom, EPSF));

        #pragma unroll
        for (int p = 0; p < 64; ++p) macc[p] = fmaf(kkx[p], w, macc[p]);
        lg = lg_next;
    }

    // Butterfly array-halving reduction (R5 win): 6 stages, 63 shuffles per
    // thread; lane l ends holding the wave total for p == l.
    float* v = macc;
#define RED_STAGE(D)                                              \
    {                                                             \
        const bool hi = (lane & (D)) != 0;                        \
        _Pragma("unroll")                                         \
        for (int i = 0; i < (D); ++i) {                           \
            float mine = hi ? v[i + (D)] : v[i];                  \
            float send = hi ? v[i] : v[i + (D)];                  \
            float got = __shfl_xor(send, (D), 64);                \
            v[i] = mine + got;                                    \
        }                                                         \
    }
    RED_STAGE(32) RED_STAGE(16) RED_STAGE(8)
    RED_STAGE(4)  RED_STAGE(2)  RED_STAGE(1)
#undef RED_STAGE
    wsum[wid][lane] = v[0];
    __syncthreads();
    if (tid < 64) {
        float s = (wsum[0][tid] + wsum[1][tid]) + (wsum[2][tid] + wsum[3][tid]);
        atomicAdd(&m[n * 64 + tid], s);   // poison-bias base: -3e-13, negligible
    }

    // Publish, then count blocks. Fence orders this block's m-atomics before
    // its counter-add at device scope (rocPRIM lookback pattern).
    __threadfence();
    __syncthreads();
    if (tid == 0) {
        float old = atomicAdd(cnt, 1.0f);          // base -3e-13 (or 0): exact
        s_last = (fabsf(old - 511.0f) < 0.5f) ? 1 : 0;
    }
    __syncthreads();

    if (s_last) {                                  // winner: all m complete
        __threadfence();                           // acquire side
        const float mv = m[tid];                   // tid == (n,p), 256 threads
        float l = -logf(fmaxf(mv, EPSF));
        #pragma unroll
        for (int off = 32; off > 0; off >>= 1) l += __shfl_xor(l, off, 64);
        __shared__ float red2[4];
        if (lane == 0) red2[wid] = l;
        __syncthreads();
        if (tid == 0)
            out[0] = (red2[0] + red2[1] + red2[2] + red2[3]) * (1.0f / 256.0f);
    }
}

extern "C" void kernel_launch(void* const* d_in, const int* in_sizes, int n_in,
                              void* d_out, int out_size, void* d_ws, size_t ws_size,
                              hipStream_t stream) {
    const float* logits = (const float*)d_in[0];  // [4,1,32,128,128] fp32
    const float* pts    = (const float*)d_in[1];  // [4,64,3] fp32
    float* ws  = (float*)d_ws;                    // 257 floats used
    float* out = (float*)d_out;                   // scalar fp32

    k_fused<<<dim3(512), dim3(256), 0, stream>>>(logits, pts, ws, out);
}

// Round 9
// 78.013 us; speedup vs baseline: 1.3062x; 1.3062x over previous
//
#include <hip/hip_runtime.h>
#include <math.h>

// Problem constants (fixed by reference)
constexpr int N_ = 4, P_ = 64, Z_ = 32, Y_ = 128, X_ = 128;
constexpr float EPSF = 1e-8f;
constexpr float INV2S2 = 0.125f;   // 1/(2*sigma^2), sigma = 2

typedef float v2f __attribute__((ext_vector_type(2)));

// bf16 round-to-nearest-even, packed pair {lo=e0, hi=e1}. bf16 keeps fp32's
// exponent range -> NO far-field flush (critical: w = s/max(denom,1e-8) can
// be ~1e8, so flushing tiny K to 0 would break m by O(1); f16 would do that,
// bf16 does not). Rel err 2^-9 ~= 0.4% -> loss abs err ~0.004 << 0.1525.
__device__ __forceinline__ unsigned pack_bf16x2(float e0, float e1) {
    unsigned u0 = __float_as_uint(e0), u1 = __float_as_uint(e1);
    u0 = u0 + 0x7fffu + ((u0 >> 16) & 1u);   // RNE
    u1 = u1 + 0x7fffu + ((u1 >> 16) & 1u);
    return (u0 >> 16) | (u1 & 0xffff0000u);
}

// ---------------------------------------------------------------------------
// Main kernel (R5 structure — best measured — with two throughput halvings):
//  * kzy tile stored as PACKED bf16 pairs in LDS: 8 b128 reads/pass (was 16).
//  * inner math on float2 ext-vectors -> v_pk_{mul,add,fma}_f32 (fp32 peak on
//    CDNA4 requires packed ops; scalar fma is half rate). All arithmetic
//    stays fp32 after unpack (unpack = shl16 / and — exact bf16->fp32).
// Grid: 512 blocks = (n, z, y-half, x-half); 256 threads = 4 waves; each wave
// owns one y-row per pass (16 passes), each thread one x-column.
// NO device fence / single-kernel finish: R8 measured +23 us for that tail
// (__threadfence = per-block L2 writeback). Private part[] slots, 2 kernels.
// ---------------------------------------------------------------------------
__global__ __launch_bounds__(256, 2) void k_fused(const float* __restrict__ logits,
                                                  const float* __restrict__ pts,
                                                  float* __restrict__ part) {
    const int b = blockIdx.x;          // 512 blocks: [n:2][z:5][yh:1][xh:1]
    const int n  = b >> 7;
    const int z  = (b >> 2) & 31;
    const int y0 = ((b >> 1) & 1) * 64;
    const int x0 = (b & 1) * 64;

    const int tid = threadIdx.x;
    const int lane = tid & 63;
    const int wid = tid >> 6;

    __shared__ float ptsn[192];        // pts[n] = [64][3]
    __shared__ unsigned kzyp[64 * 32]; // [row][p-pair] packed bf16x2, 8 KB
    __shared__ float wsum[4][64];

    if (tid < 192) ptsn[tid] = pts[n * 192 + tid];
    __syncthreads();

    // kzy tile: 2048 packed pairs / 256 threads = 8 per thread (16 exps).
    for (int i = tid; i < 64 * 32; i += 256) {
        int row = i >> 5, j = i & 31;
        int p0 = j * 2;
        float dz0 = (float)z - ptsn[p0 * 3 + 0];
        float dy0 = (float)(y0 + row) - ptsn[p0 * 3 + 1];
        float dz1 = (float)z - ptsn[p0 * 3 + 3];
        float dy1 = (float)(y0 + row) - ptsn[p0 * 3 + 4];
        float e0 = __expf(-(dz0 * dz0 + dy0 * dy0) * INV2S2);
        float e1 = __expf(-(dz1 * dz1 + dy1 * dy1) * INV2S2);
        kzyp[i] = pack_bf16x2(e0, e1);
    }

    const int x = x0 + lane;
    float kxr[64], macc[64];
    #pragma unroll
    for (int p = 0; p < 64; ++p) {
        float dx = (float)x - ptsn[p * 3 + 2];
        kxr[p] = __expf(-dx * dx * INV2S2);   // fp32 (exact range)
        macc[p] = 0.0f;
    }
    __syncthreads();

    v2f* kx2 = (v2f*)kxr;              // pair j = {p=2j, p=2j+1}
    v2f* m2  = (v2f*)macc;

    const float* lbase = logits + (size_t)((n * Z_ + z) * Y_ + y0) * X_ + x;

    float lg = lbase[wid * X_];        // prefetch pass-0 logit
    #pragma unroll 1
    for (int pass = 0; pass < 16; ++pass) {
        const int row = pass * 4 + wid;           // wave-uniform row
        float lg_next = 0.0f;
        if (pass < 15) lg_next = lbase[(row + 4) * X_];   // prefetch next pass

        const uint4* kr = (const uint4*)(&kzyp[row * 32]); // 8 b128/pass
        v2f kkx2[32];
        v2f da = (v2f)(0.f), db = (v2f)(0.f), dc = (v2f)(0.f), dd = (v2f)(0.f);
        #pragma unroll
        for (int q = 0; q < 8; ++q) {
            const uint4 u4 = kr[q];               // broadcast b128 read
            v2f b0, b1, b2, b3;                   // exact bf16->fp32 unpack
            b0.x = __uint_as_float(u4.x << 16); b0.y = __uint_as_float(u4.x & 0xffff0000u);
            b1.x = __uint_as_float(u4.y << 16); b1.y = __uint_as_float(u4.y & 0xffff0000u);
            b2.x = __uint_as_float(u4.z << 16); b2.y = __uint_as_float(u4.z & 0xffff0000u);
            b3.x = __uint_as_float(u4.w << 16); b3.y = __uint_as_float(u4.w & 0xffff0000u);
            v2f k0 = b0 * kx2[q * 4 + 0];         // v_pk_mul_f32
            v2f k1 = b1 * kx2[q * 4 + 1];
            v2f k2 = b2 * kx2[q * 4 + 2];
            v2f k3 = b3 * kx2[q * 4 + 3];
            da += k0; db += k1; dc += k2; dd += k3;   // v_pk_add_f32
            kkx2[q * 4 + 0] = k0; kkx2[q * 4 + 1] = k1;
            kkx2[q * 4 + 2] = k2; kkx2[q * 4 + 3] = k3;
        }
        const v2f dsum = (da + db) + (dc + dd);
        const float denom = dsum.x + dsum.y;
        // w = sigmoid(lg)/max(denom,EPS) = 1/((1+e^-lg)*max(denom,EPS))
        const float w = 1.0f / ((1.0f + __expf(-lg)) * fmaxf(denom, EPSF));
        const v2f wv = (v2f)(w);

        #pragma unroll
        for (int j = 0; j < 32; ++j)              // v_pk_fma_f32
            m2[j] = __builtin_elementwise_fma(kkx2[j], wv, m2[j]);
        lg = lg_next;
    }

    // Butterfly array-halving reduction (R5 win): 6 stages, 63 shuffles per
    // thread; lane l ends holding the wave total for p == l.
    float* v = macc;
#define RED_STAGE(D)                                              \
    {                                                             \
        const bool hi = (lane & (D)) != 0;                        \
        _Pragma("unroll")                                         \
        for (int i = 0; i < (D); ++i) {                           \
            float mine = hi ? v[i + (D)] : v[i];                  \
            float send = hi ? v[i] : v[i + (D)];                  \
            float got = __shfl_xor(send, (D), 64);                \
            v[i] = mine + got;                                    \
        }                                                         \
    }
    RED_STAGE(32) RED_STAGE(16) RED_STAGE(8)
    RED_STAGE(4)  RED_STAGE(2)  RED_STAGE(1)
#undef RED_STAGE
    wsum[wid][lane] = v[0];
    __syncthreads();
    if (tid < 64) {
        float s = (wsum[0][tid] + wsum[1][tid]) + (wsum[2][tid] + wsum[3][tid]);
        part[b * 64 + tid] = s;        // private slot: plain store, no atomic
    }
}

// ---------------------------------------------------------------------------
// Finish kernel: m[n][p] = sum of that n's 128 block-partials, then
// loss = mean_{n,p} -log(max(m, EPS)). 1 block x 1024 threads, 4-way split
// of the partial sum per (n,p), combined in LDS. (R5-proven; the in-kernel
// fence/atomic finish measured +23 us in R8 — do not re-fuse.)
// ---------------------------------------------------------------------------
__global__ __launch_bounds__(1024) void k_finish(const float* __restrict__ part,
                                                 float* __restrict__ out) {
    const int t = threadIdx.x;
    const int pair = t & 255;          // (n,p): n = pair>>6, p = pair&63
    const int quarter = t >> 8;        // which 32-block slice
    const int n = pair >> 6, p = pair & 63;

    const float* base = part + (size_t)(n * 128 + quarter * 32) * 64 + p;
    float s0 = 0.f, s1 = 0.f, s2 = 0.f, s3 = 0.f;
    #pragma unroll 2
    for (int j = 0; j < 32; j += 4) {  // independent accumulators
        s0 += base[(j + 0) * 64];
        s1 += base[(j + 1) * 64];
        s2 += base[(j + 2) * 64];
        s3 += base[(j + 3) * 64];
    }
    __shared__ float red[4][256];
    red[quarter][pair] = (s0 + s1) + (s2 + s3);
    __syncthreads();

    if (t < 256) {
        const float m = (red[0][t] + red[1][t]) + (red[2][t] + red[3][t]);
        float l = -logf(fmaxf(m, EPSF));
        #pragma unroll
        for (int off = 32; off > 0; off >>= 1) l += __shfl_xor(l, off, 64);
        __shared__ float red2[4];
        if ((t & 63) == 0) red2[t >> 6] = l;
        __syncthreads();
        if (t == 0) out[0] = (red2[0] + red2[1] + red2[2] + red2[3]) * (1.0f / 256.0f);
    }
}

extern "C" void kernel_launch(void* const* d_in, const int* in_sizes, int n_in,
                              void* d_out, int out_size, void* d_ws, size_t ws_size,
                              hipStream_t stream) {
    const float* logits = (const float*)d_in[0];  // [4,1,32,128,128] fp32
    const float* pts    = (const float*)d_in[1];  // [4,64,3] fp32
    float* part = (float*)d_ws;                   // 512*64 floats = 128 KB
    float* out  = (float*)d_out;                  // scalar fp32

    k_fused<<<dim3(512), dim3(256), 0, stream>>>(logits, pts, part);
    k_finish<<<dim3(1), dim3(1024), 0, stream>>>(part, out);
}

// Round 10
// 66.035 us; speedup vs baseline: 1.5432x; 1.1814x over previous
//
#include <hip/hip_runtime.h>
#include <math.h>

// Problem constants (fixed by reference)
constexpr int N_ = 4, P_ = 64, Z_ = 32, Y_ = 128, X_ = 128;
constexpr float EPSF = 1e-8f;
constexpr float INV2S2 = 0.125f;   // 1/(2*sigma^2), sigma = 2

typedef short v8s __attribute__((ext_vector_type(8)));  // 8 bf16 (4 VGPRs)
typedef float v4f __attribute__((ext_vector_type(4)));  // MFMA C/D

// fp32 -> bf16 (RNE). bf16 keeps fp32's exponent: no far-field flush (w can
// be ~1e8 and K ~1e-30; both representable). Rel err 2^-9 -> loss err ~0.02.
__device__ __forceinline__ short bf16(float f) {
    unsigned u = __float_as_uint(f);
    u = u + 0x7fffu + ((u >> 16) & 1u);
    return (short)(u >> 16);
}

// ---------------------------------------------------------------------------
// MFMA main kernel. Grid: 256 blocks = (n, z, y-half); 256 threads = 4 waves.
// Per block (y-slab of 64 rows x full 128 x):
//   GEMM1 (mfma_f32_16x16x32_bf16): denom[y][x] = sum_p kzy[y][p]*kx[p][x]
//          M=64 (y: wave w owns rows w*16+..), N=128 (x: 8 tiles), K=64 (p).
//   W[y][x] = sigmoid(logit)/max(denom,EPS), bf16 -> LDS (layout transform).
//   GEMM2: D2[p][y] = sum_x kx[p][x]*W[y][x]
//          M=64 (p: wave w owns w*16+..), N=64 (y: 4 tiles), K=128 (x).
//   macc[p] += sum_y kzy[y][p]*D2[p][y]  (16 elems/lane, in-register).
// Fragment layouts (docs, HW-verified): A[m=lane&15][k=quad*8+j],
// B[k=quad*8+j][n=lane&15], C/D: col=lane&15, row=quad*4+reg.
// A-frags & epilogue kzy are computed ANALYTICALLY in-register (separable
// exp) — no LDS staging. kx/W tiles live in LDS with XOR chunk swizzle
// (chunk' = chunk ^ (row & (nchunks-1))) so fragment reads (row stride =
// 128/256 B) spread across banks instead of 16-way conflicting.
// Rationale: R5-R9 showed the scalar loop is stall-bound at ~25 us and
// insensitive to tweaks; MFMA moves the 536 MFLOP to the matrix pipe.
// ---------------------------------------------------------------------------
__global__ __launch_bounds__(256) void k_main(const float* __restrict__ logits,
                                              const float* __restrict__ pts,
                                              float* __restrict__ part) {
    const int b = blockIdx.x;          // [n:2][z:5][yh:1]
    const int n  = b >> 6;
    const int z  = (b >> 1) & 31;
    const int y0 = (b & 1) * 64;

    const int tid  = threadIdx.x;
    const int lane = tid & 63;
    const int w    = tid >> 6;         // wave 0..3
    const int m    = lane & 15;        // row/col-in-tile index
    const int quad = lane >> 4;        // 0..3

    __shared__ float ptsn[192];        // pts[n] = [64][3]
    __shared__ short kxTB[128 * 64];   // [x][p] bf16, 8-chunk XOR swizzle
    __shared__ short WB[64 * 128];     // [y-local][x] bf16, 16-chunk swizzle
    __shared__ float psum[64];

    if (tid < 192) ptsn[tid] = pts[n * 192 + tid];
    __syncthreads();

    // kx table: 8192 exps / 256 threads. Store at swizzled chunk.
    for (int i = tid; i < 128 * 64; i += 256) {
        int x = i >> 6, p = i & 63;
        float dx = (float)x - ptsn[p * 3 + 2];
        float e = __expf(-dx * dx * INV2S2);
        kxTB[x * 64 + (((p >> 3) ^ (x & 7)) * 8) + (p & 7)] = bf16(e);
    }

    // GEMM1 A-frags (kzy rows) analytically: 16 exps/lane. quad-uniform
    // ptsn reads broadcast.
    v8s a1[2];
    {
        float yv = (float)(y0 + w * 16 + m);
        #pragma unroll
        for (int ks = 0; ks < 2; ++ks) {
            #pragma unroll
            for (int j = 0; j < 8; ++j) {
                int p = ks * 32 + quad * 8 + j;
                float dz = (float)z - ptsn[p * 3 + 0];
                float dy = yv - ptsn[p * 3 + 1];
                a1[ks][j] = bf16(__expf(-(dz * dz + dy * dy) * INV2S2));
            }
        }
    }
    __syncthreads();                   // kxTB ready

    // GEMM1: wave w -> M-tile w, N-tiles 0..7, K = 2 mfma steps.
    v4f acc1[8];
    #pragma unroll
    for (int nt = 0; nt < 8; ++nt) acc1[nt] = (v4f)(0.f);
    #pragma unroll
    for (int ks = 0; ks < 2; ++ks) {
        #pragma unroll
        for (int nt = 0; nt < 8; ++nt) {
            int row = nt * 16 + m;     // x
            int c = ks * 4 + quad;     // p-chunk
            v8s bf = *(const v8s*)&kxTB[row * 64 + ((c ^ (row & 7)) * 8)];
            acc1[nt] = __builtin_amdgcn_mfma_f32_16x16x32_bf16(a1[ks], bf, acc1[nt], 0, 0, 0);
        }
    }

    // W = sigmoid(logit)*rcp(max(denom,EPS)) -> WB (bf16, swizzled).
    // Loads first (ILP), then math. Each logit read exactly once grid-wide;
    // 16 lanes read 64 B segments.
    {
        const float* lb = logits + (size_t)((n * Z_ + z) * Y_ + y0) * X_;
        float lgs[8][4];
        #pragma unroll
        for (int nt = 0; nt < 8; ++nt)
            #pragma unroll
            for (int reg = 0; reg < 4; ++reg)
                lgs[nt][reg] = lb[(w * 16 + quad * 4 + reg) * 128 + nt * 16 + m];
        #pragma unroll
        for (int nt = 0; nt < 8; ++nt) {
            #pragma unroll
            for (int reg = 0; reg < 4; ++reg) {
                int yl = w * 16 + quad * 4 + reg;
                int x  = nt * 16 + m;
                float wv = 1.0f / ((1.0f + __expf(-lgs[nt][reg])) *
                                   fmaxf(acc1[nt][reg], EPSF));
                WB[yl * 128 + (((x >> 3) ^ (yl & 15)) * 8) + (x & 7)] = bf16(wv);
            }
        }
    }

    // GEMM2 A-frags (kx row p = w*16+m) analytically: 16 exps/lane.
    v8s a2[4];
    {
        float px = ptsn[(w * 16 + m) * 3 + 2];
        #pragma unroll
        for (int ks = 0; ks < 4; ++ks) {
            #pragma unroll
            for (int j = 0; j < 8; ++j) {
                float dx = (float)(ks * 32 + quad * 8 + j) - px;
                a2[ks][j] = bf16(__expf(-dx * dx * INV2S2));
            }
        }
    }
    __syncthreads();                   // WB ready

    // GEMM2: wave w -> M-tile w (p), N-tiles 0..3 (y), K = 4 mfma steps (x).
    v4f acc2[4];
    #pragma unroll
    for (int nt = 0; nt < 4; ++nt) acc2[nt] = (v4f)(0.f);
    #pragma unroll
    for (int ks = 0; ks < 4; ++ks) {
        #pragma unroll
        for (int nt = 0; nt < 4; ++nt) {
            int row = nt * 16 + m;     // y-local
            int c = ks * 4 + quad;     // x-chunk
            v8s bf = *(const v8s*)&WB[row * 128 + ((c ^ (row & 15)) * 8)];
            acc2[nt] = __builtin_amdgcn_mfma_f32_16x16x32_bf16(a2[ks], bf, acc2[nt], 0, 0, 0);
        }
    }

    // Epilogue: s[reg] = sum_nt kzy[y][p]*D2[p][y]; p = w*16+quad*4+reg,
    // y = y0+nt*16+m. kzy analytic (16 exps; quad-uniform ptsn broadcast).
    float s[4] = {0.f, 0.f, 0.f, 0.f};
    #pragma unroll
    for (int reg = 0; reg < 4; ++reg) {
        int p = w * 16 + quad * 4 + reg;
        float pz = ptsn[p * 3 + 0], py = ptsn[p * 3 + 1];
        float dz = (float)z - pz;
        #pragma unroll
        for (int nt = 0; nt < 4; ++nt) {
            float dy = (float)(y0 + nt * 16 + m) - py;
            float kzy = __expf(-(dz * dz + dy * dy) * INV2S2);
            s[reg] = fmaf(acc2[nt][reg], kzy, s[reg]);
        }
    }
    // Reduce over the 16 y-lanes (low 4 lane bits).
    #pragma unroll
    for (int reg = 0; reg < 4; ++reg)
        #pragma unroll
        for (int off = 1; off < 16; off <<= 1)
            s[reg] += __shfl_xor(s[reg], off, 64);
    if (m == 0) {
        #pragma unroll
        for (int reg = 0; reg < 4; ++reg)
            psum[w * 16 + quad * 4 + reg] = s[reg];
    }
    __syncthreads();
    if (tid < 64) part[b * 64 + tid] = psum[tid];   // private slot, no atomic
}

// ---------------------------------------------------------------------------
// Finish: m[n][p] = sum of that n's 64 block-partials; loss = mean(-log(...)).
// 1 block x 1024 threads: 4 threads per (n,p), 16 partials each, LDS combine.
// (R8 proved the in-kernel fence finish costs +23 us — keep 2 dispatches.)
// ---------------------------------------------------------------------------
__global__ __launch_bounds__(1024) void k_finish(const float* __restrict__ part,
                                                 float* __restrict__ out) {
    const int t = threadIdx.x;
    const int pair = t & 255;          // (n,p)
    const int quarter = t >> 8;        // 16-block slice
    const int n = pair >> 6, p = pair & 63;

    const float* base = part + (size_t)(n * 64 + quarter * 16) * 64 + p;
    float s0 = 0.f, s1 = 0.f, s2 = 0.f, s3 = 0.f;
    #pragma unroll
    for (int j = 0; j < 16; j += 4) {
        s0 += base[(j + 0) * 64];
        s1 += base[(j + 1) * 64];
        s2 += base[(j + 2) * 64];
        s3 += base[(j + 3) * 64];
    }
    __shared__ float red[4][256];
    red[quarter][pair] = (s0 + s1) + (s2 + s3);
    __syncthreads();

    if (t < 256) {
        const float mv = (red[0][t] + red[1][t]) + (red[2][t] + red[3][t]);
        float l = -logf(fmaxf(mv, EPSF));
        #pragma unroll
        for (int off = 32; off > 0; off >>= 1) l += __shfl_xor(l, off, 64);
        __shared__ float red2[4];
        if ((t & 63) == 0) red2[t >> 6] = l;
        __syncthreads();
        if (t == 0) out[0] = (red2[0] + red2[1] + red2[2] + red2[3]) * (1.0f / 256.0f);
    }
}

extern "C" void kernel_launch(void* const* d_in, const int* in_sizes, int n_in,
                              void* d_out, int out_size, void* d_ws, size_t ws_size,
                              hipStream_t stream) {
    const float* logits = (const float*)d_in[0];  // [4,1,32,128,128] fp32
    const float* pts    = (const float*)d_in[1];  // [4,64,3] fp32
    float* part = (float*)d_ws;                   // 256*64 floats = 64 KB
    float* out  = (float*)d_out;                  // scalar fp32

    k_main<<<dim3(256), dim3(256), 0, stream>>>(logits, pts, part);
    k_finish<<<dim3(1), dim3(1024), 0, stream>>>(part, out);
}